// Round 3
// baseline (234.848 us; speedup 1.0000x reference)
//
#include <hip/hip_runtime.h>
#include <math.h>

#define B_  2048
#define H_  256
#define IN_ 64

// Transposed weights (k-major) in a device global, rewritten every launch by prep_t.
// Wt_h[k][c] = wh[c][k] (256x256), Wt_o[k][c] = wout[c][k] (256x256), Wt_x[k][c] = wx[c][k] (64x256)
#define WT_H 0
#define WT_O (256 * 256)
#define WT_X (2 * 256 * 256)
__device__ float g_wt[(256 + 256 + 64) * 256];

__global__ void prep_t(const float* __restrict__ wh, const float* __restrict__ wo,
                       const float* __restrict__ wx) {
  int tid = blockIdx.x * 256 + threadIdx.x;   // 65536 threads
  int c = tid >> 8, k = tid & 255;            // reads coalesced along k
  g_wt[WT_H + k * 256 + c] = wh[c * 256 + k];
  g_wt[WT_O + k * 256 + c] = wo[c * 256 + k];
  if (tid < 64 * 256) {
    int c2 = tid >> 6, k2 = tid & 63;
    g_wt[WT_X + k2 * 256 + c2] = wx[c2 * 64 + k2];
  }
}

// Accumulate acc[s][t] += v[s][k] * W[c=32t+cg][k] over n k's starting at kb.
// Wt is k-major (row stride 256); vt is LDS [k][8 samples] fp64.
__device__ __forceinline__ void accum_k(double (&acc)[8][8], const float* __restrict__ Wt,
                                        const double* vt, int kb, int n, int cg) {
#pragma unroll 2
  for (int kk = 0; kk < n; ++kk) {
    int k = kb + kk;
    const float* wp = Wt + k * 256 + cg;   // lanes cg=0..31 -> 128B coalesced segments
    const double* vp = vt + k * 8;         // wave-uniform per kslot -> LDS broadcast
    double wd[8], vd[8];
#pragma unroll
    for (int t = 0; t < 8; ++t) wd[t] = (double)wp[32 * t];
#pragma unroll
    for (int s = 0; s < 8; ++s) vd[s] = vp[s];
#pragma unroll
    for (int s = 0; s < 8; ++s)
#pragma unroll
      for (int t = 0; t < 8; ++t)
        acc[s][t] = fma(vd[s], wd[t], acc[s][t]);   // v_fma_f64: exact products, fp64 acc
  }
}

__device__ __forceinline__ void zero_acc(double (&acc)[8][8]) {
#pragma unroll
  for (int s = 0; s < 8; ++s)
#pragma unroll
    for (int t = 0; t < 8; ++t) acc[s][t] = 0.0;
}

// y64 layout [s][c]: lanes (cg, cg+32) and 8 waves hold disjoint k-partials of the
// same (s,c): LDS atomic add accumulates them (proven correct in R2 — matched the
// independent MFMA path of R1 bit-near-exactly).
__device__ __forceinline__ void ds_add(double* y64, double (&acc)[8][8], int cg) {
#pragma unroll
  for (int s = 0; s < 8; ++s)
#pragma unroll
    for (int t = 0; t < 8; ++t)
      atomicAdd(&y64[s * 256 + 32 * t + cg], acc[s][t]);
}

__global__ __launch_bounds__(512, 2) void jacde_fp64(
    const float* __restrict__ h_g, const float* __restrict__ x_g,
    const float* __restrict__ xd_g, const float* __restrict__ b0,
    const float* __restrict__ b1, float* __restrict__ out) {

  __shared__ double vtA[256 * 8];   // activation A-buffer [k][s] fp64
  __shared__ double vtB[256 * 8];
  __shared__ double vtx[64 * 8];    // x   [k][s]
  __shared__ double vtxd[64 * 8];   // xdot[k][s]
  __shared__ double y64a[8 * 256];  // matvec outputs [s][c]
  __shared__ double y64b[8 * 256];
  __shared__ float  dre[256 * 8];   // relu gate [c][s] (exact 0/1)
  __shared__ double dta[256 * 8];   // dtanh [c][s]
  __shared__ double hd64[8 * 256];  // h_dot accumulator [s][c]

  const int tid = threadIdx.x;
  const int w = tid >> 6;           // wave 0..7 -> k-range [32w, 32w+32)
  const int lane = tid & 63;
  const int cg = lane & 31;         // owns cols {32t + cg : t<8}
  const int ks = lane >> 5;         // k-half within wave's range
  const int r0 = blockIdx.x * 8;    // batch rows

  const float* Wt_h = g_wt + WT_H;
  const float* Wt_o = g_wt + WT_O;
  const float* Wt_x = g_wt + WT_X;

  // ---- stage inputs to fp64 LDS; zero reduction buffers ----
#pragma unroll
  for (int j = 0; j < 4; ++j) {
    int idx = tid + 512 * j;              // k fast -> coalesced global reads
    int k = idx & 255, s = idx >> 8;
    vtA[k * 8 + s] = (double)h_g[(size_t)(r0 + s) * H_ + k];
    y64a[idx] = 0.0; y64b[idx] = 0.0;
  }
  {
    int k = tid & 63, s = tid >> 6;       // 512 = 64k x 8s exactly
    vtx[k * 8 + s]  = (double)x_g[(size_t)(r0 + s) * IN_ + k];
    vtxd[k * 8 + s] = (double)xd_g[(size_t)(r0 + s) * IN_ + k];
  }
  __syncthreads();

  double acc[8][8];
  const int kb  = 32 * w + 16 * ks;       // h/k-256 range start (16 iters)
  const int kbx = 8 * w + 4 * ks;         // x/k-64 range start (4 iters)

  // ---- l1 = h@wh^T + x@wx^T (bias added in gate); s = xdot@wx^T ----
  zero_acc(acc);
  accum_k(acc, Wt_h, vtA, kb, 16, cg);
  accum_k(acc, Wt_x, vtx, kbx, 4, cg);
  ds_add(y64a, acc, cg);
  zero_acc(acc);
  accum_k(acc, Wt_x, vtxd, kbx, 4, cg);
  ds_add(y64b, acc, cg);
  __syncthreads();

  // ---- gate1: drelu + relu (exact fp64 threshold) ----
#pragma unroll
  for (int j = 0; j < 4; ++j) {
    int idx = tid + 512 * j;              // s = idx&7 fast -> linear LDS [c][s] writes
    int s = idx & 7, c = idx >> 3;
    int li = s * 256 + c;
    double l1 = y64a[li] + (double)b0[c];
    dre[idx] = (l1 > 0.0) ? 1.f : 0.f;
    vtB[idx] = (l1 > 0.0) ? l1 : 0.0;     // relu_val
    y64a[li] = 0.0;
  }
  __syncthreads();

  // ---- lout = relu@wout^T ----
  zero_acc(acc);
  accum_k(acc, Wt_o, vtB, kb, 16, cg);
  ds_add(y64a, acc, cg);
  __syncthreads();

  // ---- gate2: dtanh (fp64 tanh); u0 = drelu * s ----
#pragma unroll
  for (int j = 0; j < 4; ++j) {
    int idx = tid + 512 * j;
    int s = idx & 7, c = idx >> 3;
    int li = s * 256 + c;
    double lo = y64a[li] + (double)b1[c];
    double t = tanh(lo);
    dta[idx] = 1.0 - t * t;
    vtA[idx] = (double)dre[idx] * y64b[li];
    y64a[li] = 0.0; y64b[li] = 0.0;
  }
  __syncthreads();

  // ---- jx = dtanh * (u0@wout^T) ----
  zero_acc(acc);
  accum_k(acc, Wt_o, vtA, kb, 16, cg);
  ds_add(y64a, acc, cg);
  __syncthreads();

#pragma unroll
  for (int j = 0; j < 4; ++j) {
    int idx = tid + 512 * j;
    int s = idx & 7, c = idx >> 3;
    int li = s * 256 + c;
    double v = dta[idx] * y64a[li];
    hd64[li] = v;                          // h_dot = jx
    vtB[idx] = v;                          // curr_term
    y64a[li] = 0.0;
  }
  __syncthreads();

  // ---- 8x: curr <- dtanh*((drelu*(curr@wh^T))@wout^T); h_dot += curr ----
  for (int it = 0; it < 8; ++it) {
    zero_acc(acc);
    accum_k(acc, Wt_h, vtB, kb, 16, cg);
    ds_add(y64a, acc, cg);
    __syncthreads();
#pragma unroll
    for (int j = 0; j < 4; ++j) {
      int idx = tid + 512 * j;
      int s = idx & 7, c = idx >> 3;
      int li = s * 256 + c;
      vtA[idx] = (double)dre[idx] * y64a[li];
      y64a[li] = 0.0;
    }
    __syncthreads();

    zero_acc(acc);
    accum_k(acc, Wt_o, vtA, kb, 16, cg);
    ds_add(y64a, acc, cg);
    __syncthreads();
#pragma unroll
    for (int j = 0; j < 4; ++j) {
      int idx = tid + 512 * j;
      int s = idx & 7, c = idx >> 3;
      int li = s * 256 + c;
      double v = dta[idx] * y64a[li];
      hd64[li] += v;
      vtB[idx] = v;
      y64a[li] = 0.0;
    }
    __syncthreads();
  }

  // ---- epilogue: FP32 out (reference output dtype is float32!), c-fast coalesced ----
#pragma unroll
  for (int j = 0; j < 4; ++j) {
    int idx = tid + 512 * j;
    int c = idx & 255, s = idx >> 8;
    out[(size_t)(r0 + s) * H_ + c] = (float)hd64[s * 256 + c];
  }
}

extern "C" void kernel_launch(void* const* d_in, const int* in_sizes, int n_in,
                              void* d_out, int out_size, void* d_ws, size_t ws_size,
                              hipStream_t stream) {
  const float* h_g  = (const float*)d_in[0];
  const float* x_g  = (const float*)d_in[1];
  const float* xd_g = (const float*)d_in[2];
  const float* wx   = (const float*)d_in[3];
  const float* wh   = (const float*)d_in[4];
  const float* wo   = (const float*)d_in[5];
  const float* b0   = (const float*)d_in[6];
  const float* b1   = (const float*)d_in[7];
  prep_t<<<dim3(256), dim3(256), 0, stream>>>(wh, wo, wx);
  jacde_fp64<<<dim3(B_ / 8), dim3(512), 0, stream>>>(h_g, x_g, xd_g, b0, b1, (float*)d_out);
}

// Round 4
// 106.806 us; speedup vs baseline: 2.1988x; 2.1988x over previous
//
#include <hip/hip_runtime.h>
#include <math.h>

#define B_  2048
#define H_  256
#define IN_ 64

typedef __attribute__((ext_vector_type(8))) short bf8_t;   // 8 x bf16 (4 VGPR)
typedef __attribute__((ext_vector_type(4))) short s4_t;
typedef __attribute__((ext_vector_type(4))) float f4_t;

#define MFMA_BF16(a, b, c) __builtin_amdgcn_mfma_f32_16x16x32_bf16((a), (b), (c), 0, 0, 0)

__device__ __forceinline__ short f2bf(float f) {         // rne
  union { float f; unsigned u; } v; v.f = f;
  unsigned u = v.u + 0x7fffu + ((v.u >> 16) & 1u);
  return (short)(u >> 16);
}
__device__ __forceinline__ float bf2f(short s) {
  union { unsigned u; float f; } v; v.u = ((unsigned)(unsigned short)s) << 16;
  return v.f;
}

// load 8 consecutive floats of W[col][k0..k0+8), emit hi/lo bf16 fragments
__device__ __forceinline__ void load_wfrag2(const float* __restrict__ W, int ld, int col,
                                            int k0, bf8_t& hi, bf8_t& lo) {
  const float* p = W + (size_t)col * ld + k0;
  f4_t a = *reinterpret_cast<const f4_t*>(p);
  f4_t b = *reinterpret_cast<const f4_t*>(p + 4);
#pragma unroll
  for (int j = 0; j < 8; ++j) {
    float f = (j < 4) ? a[j] : b[j - 4];
    short h = f2bf(f);
    hi[j] = h;
    lo[j] = f2bf(f - bf2f(h));
  }
}

// A-split x W-split, 3-term (err ~2^-18 per product)
#define GEMM3(A0, A1, AH, AL, WH, WL, NK) do {                                  \
  _Pragma("unroll")                                                             \
  for (int ks = 0; ks < (NK); ++ks) {                                           \
    bf8_t ah = *reinterpret_cast<const bf8_t*>(&AH[ln][ks * 32 + lq * 8]);      \
    bf8_t al = *reinterpret_cast<const bf8_t*>(&AL[ln][ks * 32 + lq * 8]);      \
    A0 = MFMA_BF16(ah, WH[0][ks], A0);                                          \
    A0 = MFMA_BF16(ah, WL[0][ks], A0);                                          \
    A0 = MFMA_BF16(al, WH[0][ks], A0);                                          \
    A1 = MFMA_BF16(ah, WH[1][ks], A1);                                          \
    A1 = MFMA_BF16(ah, WL[1][ks], A1);                                          \
    A1 = MFMA_BF16(al, WH[1][ks], A1);                                          \
  } } while (0)

// A-split x W-hi, 2-term (err = weight truncation only, ~2^-10 rms per product)
#define GEMM2(A0, A1, AH, AL, WH, NK) do {                                      \
  _Pragma("unroll")                                                             \
  for (int ks = 0; ks < (NK); ++ks) {                                           \
    bf8_t ah = *reinterpret_cast<const bf8_t*>(&AH[ln][ks * 32 + lq * 8]);      \
    bf8_t al = *reinterpret_cast<const bf8_t*>(&AL[ln][ks * 32 + lq * 8]);      \
    A0 = MFMA_BF16(ah, WH[0][ks], A0);                                          \
    A0 = MFMA_BF16(al, WH[0][ks], A0);                                          \
    A1 = MFMA_BF16(ah, WH[1][ks], A1);                                          \
    A1 = MFMA_BF16(al, WH[1][ks], A1);                                          \
  } } while (0)

__global__ __launch_bounds__(512, 2) void jacde_mfma(
    const float* __restrict__ h_g, const float* __restrict__ x_g,
    const float* __restrict__ xd_g, const float* __restrict__ wx,
    const float* __restrict__ wh, const float* __restrict__ wo,
    const float* __restrict__ b0, const float* __restrict__ b1,
    float* __restrict__ out) {

  __shared__ short h_hi[16][264], h_lo[16][264];
  __shared__ short x_hi[16][72],  x_lo[16][72];
  __shared__ short xd_hi[16][72], xd_lo[16][72];
  __shared__ short u_hi[16][264], u_lo[16][264];
  __shared__ short v_hi[16][264], v_lo[16][264];
  __shared__ float l1_t[16][264];
  __shared__ int   fix_cnt;
  __shared__ int   fix_list[64];

  const int tid  = threadIdx.x;
  const int wv   = tid >> 6;
  const int lane = tid & 63;
  const int ln   = lane & 15;       // A row / C col-within-tile
  const int lq   = lane >> 4;       // quad
  const int r0   = blockIdx.x * 16; // batch-row base
  const int cbase = wv * 32;        // wave's output-column base

  if (tid == 0) fix_cnt = 0;

  // ---- stage activations to split-bf16 LDS ----
  for (int c = tid; c < 16 * 64; c += 512) {
    int r = c >> 6, k4 = (c & 63) * 4;
    f4_t v = *reinterpret_cast<const f4_t*>(h_g + (size_t)(r0 + r) * H_ + k4);
    s4_t shv, slv;
#pragma unroll
    for (int j = 0; j < 4; ++j) { short h = f2bf(v[j]); shv[j] = h; slv[j] = f2bf(v[j] - bf2f(h)); }
    *reinterpret_cast<s4_t*>(&h_hi[r][k4]) = shv;
    *reinterpret_cast<s4_t*>(&h_lo[r][k4]) = slv;
  }
  {
    int t2 = tid & 255;
    const float* src = (tid < 256) ? x_g : xd_g;
    short (*dh)[72] = (tid < 256) ? x_hi : xd_hi;
    short (*dl)[72] = (tid < 256) ? x_lo : xd_lo;
    int r = t2 >> 4, k4 = (t2 & 15) * 4;
    f4_t v = *reinterpret_cast<const f4_t*>(src + (size_t)(r0 + r) * IN_ + k4);
    s4_t shv, slv;
#pragma unroll
    for (int j = 0; j < 4; ++j) { short h = f2bf(v[j]); shv[j] = h; slv[j] = f2bf(v[j] - bf2f(h)); }
    *reinterpret_cast<s4_t*>(&dh[r][k4]) = shv;
    *reinterpret_cast<s4_t*>(&dl[r][k4]) = slv;
  }

  // ---- persistent weight-hi fragments (live through all 19 GEMM steps) ----
  bf8_t whf[2][8], wof[2][8];
  f4_t acc0, acc1, sacc0, sacc1;
  float dre0[4], dre1[4], dta0[4], dta1[4], hd0[4], hd1[4];

  // ---- stage 1: l1 = x@wx^T + h@wh^T + b0 (3-term);  s = xdot@wx^T (3-term) ----
  {
    bf8_t whl[2][8], wxh[2][2], wxl[2][2];
#pragma unroll
    for (int t = 0; t < 2; ++t) {
      int col = cbase + t * 16 + ln;
#pragma unroll
      for (int ks = 0; ks < 8; ++ks)
        load_wfrag2(wh, H_, col, ks * 32 + lq * 8, whf[t][ks], whl[t][ks]);
#pragma unroll
      for (int ks = 0; ks < 2; ++ks)
        load_wfrag2(wx, IN_, col, ks * 32 + lq * 8, wxh[t][ks], wxl[t][ks]);
    }
    __syncthreads();   // activations staged

    float bv0 = b0[cbase + ln], bv1 = b0[cbase + 16 + ln];
    acc0 = (f4_t){bv0, bv0, bv0, bv0};
    acc1 = (f4_t){bv1, bv1, bv1, bv1};
    GEMM3(acc0, acc1, h_hi, h_lo, whf, whl, 8);
    GEMM3(acc0, acc1, x_hi, x_lo, wxh, wxl, 2);
    sacc0 = (f4_t){0.f, 0.f, 0.f, 0.f};
    sacc1 = (f4_t){0.f, 0.f, 0.f, 0.f};
    GEMM3(sacc0, sacc1, xd_hi, xd_lo, wxh, wxl, 2);
#pragma unroll
    for (int r = 0; r < 4; ++r) {   // C/D: col=lane&15, row=quad*4+reg [m89]
      l1_t[lq * 4 + r][cbase + ln]      = acc0[r];
      l1_t[lq * 4 + r][cbase + 16 + ln] = acc1[r];
    }
  }
  __syncthreads();

  // ---- fp64 fixup of near-zero l1 (hard relu gate must match fp64 anchor) ----
  for (int e = tid; e < 16 * 256; e += 512) {
    int r = e >> 8, c = e & 255;
    if (fabsf(l1_t[r][c]) < 1e-4f) {
      int idx = atomicAdd(&fix_cnt, 1);
      if (idx < 64) fix_list[idx] = (r << 8) | c;
    }
  }
  __syncthreads();
  {
    int nfix = min(fix_cnt, 64);
    for (int e = wv; e < nfix; e += 8) {
      int rc = fix_list[e];
      int r = rc >> 8, c = rc & 255;
      const float* hrow = h_g + (size_t)(r0 + r) * H_;
      const float* wrow = wh + (size_t)c * H_;
      double sum = (double)hrow[lane]       * (double)wrow[lane]
                 + (double)hrow[lane + 64]  * (double)wrow[lane + 64]
                 + (double)hrow[lane + 128] * (double)wrow[lane + 128]
                 + (double)hrow[lane + 192] * (double)wrow[lane + 192]
                 + (double)x_g[(size_t)(r0 + r) * IN_ + lane] * (double)wx[(size_t)c * IN_ + lane];
#pragma unroll
      for (int m = 32; m; m >>= 1) sum += __shfl_xor(sum, m);
      if (lane == 0) l1_t[r][c] = (float)(sum + (double)b0[c]);
    }
  }
  __syncthreads();

  // ---- gates: relu_val (split) to u bufs; dre into registers at wave positions ----
  for (int e = tid; e < 16 * 256; e += 512) {
    int r = e >> 8, c = e & 255;
    float l1 = l1_t[r][c];
    float rv = l1 > 0.f ? l1 : 0.f;
    short hi = f2bf(rv);
    u_hi[r][c] = hi;
    u_lo[r][c] = f2bf(rv - bf2f(hi));
  }
#pragma unroll
  for (int r = 0; r < 4; ++r) {
    dre0[r] = (l1_t[lq * 4 + r][cbase + ln]      > 0.f) ? 1.f : 0.f;
    dre1[r] = (l1_t[lq * 4 + r][cbase + 16 + ln] > 0.f) ? 1.f : 0.f;
  }
  __syncthreads();

  // ---- stage 2: lout = relu@wout^T + b1 (3-term) -> dtanh ----
  {
    bf8_t wol[2][8];
#pragma unroll
    for (int t = 0; t < 2; ++t) {
      int col = cbase + t * 16 + ln;
#pragma unroll
      for (int ks = 0; ks < 8; ++ks)
        load_wfrag2(wo, H_, col, ks * 32 + lq * 8, wof[t][ks], wol[t][ks]);
    }
    float bv0 = b1[cbase + ln], bv1 = b1[cbase + 16 + ln];
    acc0 = (f4_t){bv0, bv0, bv0, bv0};
    acc1 = (f4_t){bv1, bv1, bv1, bv1};
    GEMM3(acc0, acc1, u_hi, u_lo, wof, wol, 8);
#pragma unroll
    for (int r = 0; r < 4; ++r) {
      float t0 = tanhf(acc0[r]);
      float t1 = tanhf(acc1[r]);
      dta0[r] = 1.f - t0 * t0;
      dta1[r] = 1.f - t1 * t1;
    }
  }
  __syncthreads();   // all waves done reading relu from u bufs

  // ---- u0 = dre * s (split write at wave positions) ----
#pragma unroll
  for (int r = 0; r < 4; ++r) {
    int row = lq * 4 + r;
    float v0 = dre0[r] * sacc0[r];
    float v1 = dre1[r] * sacc1[r];
    short h0 = f2bf(v0), h1 = f2bf(v1);
    u_hi[row][cbase + ln]      = h0;  u_lo[row][cbase + ln]      = f2bf(v0 - bf2f(h0));
    u_hi[row][cbase + 16 + ln] = h1;  u_lo[row][cbase + 16 + ln] = f2bf(v1 - bf2f(h1));
  }
  __syncthreads();

  // ---- jx = dta * (u0@wout^T): h_dot = jx, curr -> v bufs ----
  acc0 = (f4_t){0.f, 0.f, 0.f, 0.f};
  acc1 = (f4_t){0.f, 0.f, 0.f, 0.f};
  GEMM2(acc0, acc1, u_hi, u_lo, wof, 8);
#pragma unroll
  for (int r = 0; r < 4; ++r) {
    int row = lq * 4 + r;
    float v0 = dta0[r] * acc0[r];
    float v1 = dta1[r] * acc1[r];
    hd0[r] = v0; hd1[r] = v1;
    short h0 = f2bf(v0), h1 = f2bf(v1);
    v_hi[row][cbase + ln]      = h0;  v_lo[row][cbase + ln]      = f2bf(v0 - bf2f(h0));
    v_hi[row][cbase + 16 + ln] = h1;  v_lo[row][cbase + 16 + ln] = f2bf(v1 - bf2f(h1));
  }
  __syncthreads();

  // ---- 8x: curr <- dta*((dre*(curr@wh^T))@wout^T); h_dot += curr ----
  for (int it = 0; it < 8; ++it) {
    acc0 = (f4_t){0.f, 0.f, 0.f, 0.f};
    acc1 = (f4_t){0.f, 0.f, 0.f, 0.f};
    GEMM2(acc0, acc1, v_hi, v_lo, whf, 8);
#pragma unroll
    for (int r = 0; r < 4; ++r) {
      int row = lq * 4 + r;
      float v0 = dre0[r] * acc0[r];
      float v1 = dre1[r] * acc1[r];
      short h0 = f2bf(v0), h1 = f2bf(v1);
      u_hi[row][cbase + ln]      = h0;  u_lo[row][cbase + ln]      = f2bf(v0 - bf2f(h0));
      u_hi[row][cbase + 16 + ln] = h1;  u_lo[row][cbase + 16 + ln] = f2bf(v1 - bf2f(h1));
    }
    __syncthreads();

    acc0 = (f4_t){0.f, 0.f, 0.f, 0.f};
    acc1 = (f4_t){0.f, 0.f, 0.f, 0.f};
    GEMM2(acc0, acc1, u_hi, u_lo, wof, 8);
#pragma unroll
    for (int r = 0; r < 4; ++r) {
      int row = lq * 4 + r;
      float v0 = dta0[r] * acc0[r];
      float v1 = dta1[r] * acc1[r];
      hd0[r] += v0; hd1[r] += v1;
      if (it < 7) {
        short h0 = f2bf(v0), h1 = f2bf(v1);
        v_hi[row][cbase + ln]      = h0;  v_lo[row][cbase + ln]      = f2bf(v0 - bf2f(h0));
        v_hi[row][cbase + 16 + ln] = h1;  v_lo[row][cbase + 16 + ln] = f2bf(v1 - bf2f(h1));
      }
    }
    __syncthreads();
  }

  // ---- epilogue: fp32 out ----
#pragma unroll
  for (int r = 0; r < 4; ++r) {
    int row = lq * 4 + r;
    out[(size_t)(r0 + row) * H_ + cbase + ln]      = hd0[r];
    out[(size_t)(r0 + row) * H_ + cbase + 16 + ln] = hd1[r];
  }
}

extern "C" void kernel_launch(void* const* d_in, const int* in_sizes, int n_in,
                              void* d_out, int out_size, void* d_ws, size_t ws_size,
                              hipStream_t stream) {
  const float* h_g  = (const float*)d_in[0];
  const float* x_g  = (const float*)d_in[1];
  const float* xd_g = (const float*)d_in[2];
  const float* wx   = (const float*)d_in[3];
  const float* wh   = (const float*)d_in[4];
  const float* wo   = (const float*)d_in[5];
  const float* b0   = (const float*)d_in[6];
  const float* b1   = (const float*)d_in[7];
  jacde_mfma<<<dim3(B_ / 16), dim3(512), 0, stream>>>(
      h_g, x_g, xd_g, wx, wh, wo, b0, b1, (float*)d_out);
}

// Round 5
// 95.847 us; speedup vs baseline: 2.4502x; 1.1143x over previous
//
#include <hip/hip_runtime.h>
#include <math.h>

#define B_  2048
#define H_  256
#define IN_ 64

typedef __attribute__((ext_vector_type(8))) short bf8_t;   // 8 x bf16 (4 VGPR)
typedef __attribute__((ext_vector_type(4))) short s4_t;
typedef __attribute__((ext_vector_type(4))) float f4_t;

#define MFMA_BF16(a, b, c) __builtin_amdgcn_mfma_f32_16x16x32_bf16((a), (b), (c), 0, 0, 0)

__device__ __forceinline__ short f2bf(float f) {         // rne
  union { float f; unsigned u; } v; v.f = f;
  unsigned u = v.u + 0x7fffu + ((v.u >> 16) & 1u);
  return (short)(u >> 16);
}
__device__ __forceinline__ float bf2f(short s) {
  union { unsigned u; float f; } v; v.u = ((unsigned)(unsigned short)s) << 16;
  return v.f;
}

// Pre-split weights in MFMA B-fragment layout: element j of fragment
// [(g*NKS+ks)*64+lane] is W[c][k], c = g*16 + (lane&15), k = ks*32 + (lane>>4)*8 + j.
__device__ __align__(16) short g_whf[2][65536];   // [hi/lo] 256x256
__device__ __align__(16) short g_wof[2][65536];   // [hi/lo] 256x256
__device__ __align__(16) short g_wxf[2][16384];   // [hi/lo] 256x64

__global__ void prep_frag(const float* __restrict__ wh, const float* __restrict__ wo,
                          const float* __restrict__ wx) {
  int tid = blockIdx.x * 256 + threadIdx.x;       // 72*256 = 18432
  const float* W; short* Dh; short* Dl; int ld, ksh, o8;
  if (tid < 8192)       { W = wh; Dh = g_whf[0]; Dl = g_whf[1]; ld = 256; ksh = 3; o8 = tid; }
  else if (tid < 16384) { W = wo; Dh = g_wof[0]; Dl = g_wof[1]; ld = 256; ksh = 3; o8 = tid - 8192; }
  else if (tid < 18432) { W = wx; Dh = g_wxf[0]; Dl = g_wxf[1]; ld = 64;  ksh = 1; o8 = tid - 16384; }
  else return;
  int lane = o8 & 63;
  int gks = o8 >> 6;
  int g = gks >> ksh, ks = gks & ((1 << ksh) - 1);
  int c = g * 16 + (lane & 15);
  int k0 = ks * 32 + ((lane >> 4) & 3) * 8;
  const float* p = W + (size_t)c * ld + k0;
  bf8_t hi, lo;
#pragma unroll
  for (int j = 0; j < 8; ++j) {
    float f = p[j];
    short h = f2bf(f);
    hi[j] = h; lo[j] = f2bf(f - bf2f(h));
  }
  *reinterpret_cast<bf8_t*>(Dh + (size_t)o8 * 8) = hi;
  *reinterpret_cast<bf8_t*>(Dl + (size_t)o8 * 8) = lo;
}

// 3-term split GEMM (A-hi/lo x W-hi/lo), odd/even-ks partial accs for 4-chain ILP
#define GEMM3(A0, A1, AH, AL, WH, WL, NK) do {                                  \
  f4_t q0 = {0.f,0.f,0.f,0.f}, q1 = {0.f,0.f,0.f,0.f};                          \
  _Pragma("unroll")                                                             \
  for (int ks = 0; ks < (NK); ++ks) {                                           \
    bf8_t ah = *reinterpret_cast<const bf8_t*>(&AH[ln][ks * 32 + lq * 8]);      \
    bf8_t al = *reinterpret_cast<const bf8_t*>(&AL[ln][ks * 32 + lq * 8]);      \
    if (ks & 1) {                                                               \
      q0 = MFMA_BF16(ah, WH[0][ks], q0); q0 = MFMA_BF16(ah, WL[0][ks], q0);     \
      q0 = MFMA_BF16(al, WH[0][ks], q0);                                        \
      q1 = MFMA_BF16(ah, WH[1][ks], q1); q1 = MFMA_BF16(ah, WL[1][ks], q1);     \
      q1 = MFMA_BF16(al, WH[1][ks], q1);                                        \
    } else {                                                                    \
      A0 = MFMA_BF16(ah, WH[0][ks], A0); A0 = MFMA_BF16(ah, WL[0][ks], A0);     \
      A0 = MFMA_BF16(al, WH[0][ks], A0);                                        \
      A1 = MFMA_BF16(ah, WH[1][ks], A1); A1 = MFMA_BF16(ah, WL[1][ks], A1);     \
      A1 = MFMA_BF16(al, WH[1][ks], A1);                                        \
    }                                                                           \
  }                                                                             \
  A0 = A0 + q0; A1 = A1 + q1; } while (0)

// 2-term split GEMM (A-hi/lo x W-hi), odd/even-ks partial accs
#define GEMM2(A0, A1, AH, AL, WH, NK) do {                                      \
  f4_t q0 = {0.f,0.f,0.f,0.f}, q1 = {0.f,0.f,0.f,0.f};                          \
  _Pragma("unroll")                                                             \
  for (int ks = 0; ks < (NK); ++ks) {                                           \
    bf8_t ah = *reinterpret_cast<const bf8_t*>(&AH[ln][ks * 32 + lq * 8]);      \
    bf8_t al = *reinterpret_cast<const bf8_t*>(&AL[ln][ks * 32 + lq * 8]);      \
    if (ks & 1) {                                                               \
      q0 = MFMA_BF16(ah, WH[0][ks], q0); q0 = MFMA_BF16(al, WH[0][ks], q0);     \
      q1 = MFMA_BF16(ah, WH[1][ks], q1); q1 = MFMA_BF16(al, WH[1][ks], q1);     \
    } else {                                                                    \
      A0 = MFMA_BF16(ah, WH[0][ks], A0); A0 = MFMA_BF16(al, WH[0][ks], A0);     \
      A1 = MFMA_BF16(ah, WH[1][ks], A1); A1 = MFMA_BF16(al, WH[1][ks], A1);     \
    }                                                                           \
  }                                                                             \
  A0 = A0 + q0; A1 = A1 + q1; } while (0)

__global__ __launch_bounds__(512, 2) void jacde_mfma(
    const float* __restrict__ h_g, const float* __restrict__ x_g,
    const float* __restrict__ xd_g, const float* __restrict__ wx,
    const float* __restrict__ wh, const float* __restrict__ b0,
    const float* __restrict__ b1, float* __restrict__ out) {

  __shared__ short h_hi[16][264], h_lo[16][264];
  __shared__ short x_hi[16][72],  x_lo[16][72];
  __shared__ short xd_hi[16][72], xd_lo[16][72];
  __shared__ short u_hi[16][264], u_lo[16][264];
  __shared__ short v_hi[16][264], v_lo[16][264];
  __shared__ float l1_t[16][264];
  __shared__ int   fix_cnt;
  __shared__ int   fix_list[64];

  const int tid  = threadIdx.x;
  const int wv   = tid >> 6;
  const int lane = tid & 63;
  const int ln   = lane & 15;       // A row / C col-within-tile
  const int lq   = lane >> 4;       // quad
  const int r0   = blockIdx.x * 16; // batch-row base
  const int cbase = wv * 32;        // wave's output-column base

  if (tid == 0) fix_cnt = 0;

  // ---- stage activations to split-bf16 LDS ----
  for (int c = tid; c < 16 * 64; c += 512) {
    int r = c >> 6, k4 = (c & 63) * 4;
    f4_t v = *reinterpret_cast<const f4_t*>(h_g + (size_t)(r0 + r) * H_ + k4);
    s4_t shv, slv;
#pragma unroll
    for (int j = 0; j < 4; ++j) { short h = f2bf(v[j]); shv[j] = h; slv[j] = f2bf(v[j] - bf2f(h)); }
    *reinterpret_cast<s4_t*>(&h_hi[r][k4]) = shv;
    *reinterpret_cast<s4_t*>(&h_lo[r][k4]) = slv;
  }
  {
    int t2 = tid & 255;
    const float* src = (tid < 256) ? x_g : xd_g;
    short (*dh)[72] = (tid < 256) ? x_hi : xd_hi;
    short (*dl)[72] = (tid < 256) ? x_lo : xd_lo;
    int r = t2 >> 4, k4 = (t2 & 15) * 4;
    f4_t v = *reinterpret_cast<const f4_t*>(src + (size_t)(r0 + r) * IN_ + k4);
    s4_t shv, slv;
#pragma unroll
    for (int j = 0; j < 4; ++j) { short h = f2bf(v[j]); shv[j] = h; slv[j] = f2bf(v[j] - bf2f(h)); }
    *reinterpret_cast<s4_t*>(&dh[r][k4]) = shv;
    *reinterpret_cast<s4_t*>(&dl[r][k4]) = slv;
  }

  // ---- persistent weight-hi fragments (live through all 19 GEMM steps) ----
  bf8_t whf[2][8], wof[2][8];
  f4_t acc0, acc1, sacc0, sacc1;
  float dre0[4], dre1[4], dta0[4], dta1[4], hd0[4], hd1[4];

  // ---- stage 1: l1 = x@wx^T + h@wh^T + b0 (3-term);  s = xdot@wx^T (3-term) ----
  {
    bf8_t whl[2][8], wxh[2][2], wxl[2][2];
#pragma unroll
    for (int t = 0; t < 2; ++t) {
      int gb = wv * 2 + t;
#pragma unroll
      for (int ks = 0; ks < 8; ++ks) {
        int off = ((gb * 8 + ks) * 64 + lane) * 8;
        whf[t][ks] = *reinterpret_cast<const bf8_t*>(&g_whf[0][off]);
        whl[t][ks] = *reinterpret_cast<const bf8_t*>(&g_whf[1][off]);
      }
#pragma unroll
      for (int ks = 0; ks < 2; ++ks) {
        int off = ((gb * 2 + ks) * 64 + lane) * 8;
        wxh[t][ks] = *reinterpret_cast<const bf8_t*>(&g_wxf[0][off]);
        wxl[t][ks] = *reinterpret_cast<const bf8_t*>(&g_wxf[1][off]);
      }
    }
    __syncthreads();   // activations staged

    float bv0 = b0[cbase + ln], bv1 = b0[cbase + 16 + ln];
    acc0 = (f4_t){bv0, bv0, bv0, bv0};
    acc1 = (f4_t){bv1, bv1, bv1, bv1};
    GEMM3(acc0, acc1, h_hi, h_lo, whf, whl, 8);
    GEMM3(acc0, acc1, x_hi, x_lo, wxh, wxl, 2);
    sacc0 = (f4_t){0.f, 0.f, 0.f, 0.f};
    sacc1 = (f4_t){0.f, 0.f, 0.f, 0.f};
    GEMM3(sacc0, sacc1, xd_hi, xd_lo, wxh, wxl, 2);
#pragma unroll
    for (int r = 0; r < 4; ++r) {   // C/D: col=lane&15, row=quad*4+reg [m89]
      l1_t[lq * 4 + r][cbase + ln]      = acc0[r];
      l1_t[lq * 4 + r][cbase + 16 + ln] = acc1[r];
    }
  }
  __syncthreads();

  // ---- fp64 fixup of near-zero l1 (hard relu gate must match fp64 anchor) ----
  for (int e = tid; e < 16 * 256; e += 512) {
    int r = e >> 8, c = e & 255;
    if (fabsf(l1_t[r][c]) < 1e-4f) {
      int idx = atomicAdd(&fix_cnt, 1);
      if (idx < 64) fix_list[idx] = (r << 8) | c;
    }
  }
  __syncthreads();
  {
    int nfix = min(fix_cnt, 64);
    for (int e = wv; e < nfix; e += 8) {
      int rc = fix_list[e];
      int r = rc >> 8, c = rc & 255;
      const float* hrow = h_g + (size_t)(r0 + r) * H_;
      const float* wrow = wh + (size_t)c * H_;
      double sum = (double)hrow[lane]       * (double)wrow[lane]
                 + (double)hrow[lane + 64]  * (double)wrow[lane + 64]
                 + (double)hrow[lane + 128] * (double)wrow[lane + 128]
                 + (double)hrow[lane + 192] * (double)wrow[lane + 192]
                 + (double)x_g[(size_t)(r0 + r) * IN_ + lane] * (double)wx[(size_t)c * IN_ + lane];
#pragma unroll
      for (int m = 32; m; m >>= 1) sum += __shfl_xor(sum, m);
      if (lane == 0) l1_t[r][c] = (float)(sum + (double)b0[c]);
    }
  }
  __syncthreads();

  // ---- gates: relu_val (split) to u bufs; dre into registers at wave positions ----
  for (int e = tid; e < 16 * 256; e += 512) {
    int r = e >> 8, c = e & 255;
    float l1 = l1_t[r][c];
    float rv = l1 > 0.f ? l1 : 0.f;
    short hi = f2bf(rv);
    u_hi[r][c] = hi;
    u_lo[r][c] = f2bf(rv - bf2f(hi));
  }
#pragma unroll
  for (int r = 0; r < 4; ++r) {
    dre0[r] = (l1_t[lq * 4 + r][cbase + ln]      > 0.f) ? 1.f : 0.f;
    dre1[r] = (l1_t[lq * 4 + r][cbase + 16 + ln] > 0.f) ? 1.f : 0.f;
  }
  __syncthreads();

  // ---- stage 2: lout = relu@wout^T + b1 (3-term) -> dtanh ----
  {
    bf8_t wol[2][8];
#pragma unroll
    for (int t = 0; t < 2; ++t) {
      int gb = wv * 2 + t;
#pragma unroll
      for (int ks = 0; ks < 8; ++ks) {
        int off = ((gb * 8 + ks) * 64 + lane) * 8;
        wof[t][ks] = *reinterpret_cast<const bf8_t*>(&g_wof[0][off]);
        wol[t][ks] = *reinterpret_cast<const bf8_t*>(&g_wof[1][off]);
      }
    }
    float bv0 = b1[cbase + ln], bv1 = b1[cbase + 16 + ln];
    acc0 = (f4_t){bv0, bv0, bv0, bv0};
    acc1 = (f4_t){bv1, bv1, bv1, bv1};
    GEMM3(acc0, acc1, u_hi, u_lo, wof, wol, 8);
#pragma unroll
    for (int r = 0; r < 4; ++r) {
      float t0 = tanhf(acc0[r]);
      float t1 = tanhf(acc1[r]);
      dta0[r] = 1.f - t0 * t0;
      dta1[r] = 1.f - t1 * t1;
    }
  }
  __syncthreads();   // all waves done reading relu from u bufs

  // ---- u0 = dre * s (split write at wave positions) ----
#pragma unroll
  for (int r = 0; r < 4; ++r) {
    int row = lq * 4 + r;
    float v0 = dre0[r] * sacc0[r];
    float v1 = dre1[r] * sacc1[r];
    short h0 = f2bf(v0), h1 = f2bf(v1);
    u_hi[row][cbase + ln]      = h0;  u_lo[row][cbase + ln]      = f2bf(v0 - bf2f(h0));
    u_hi[row][cbase + 16 + ln] = h1;  u_lo[row][cbase + 16 + ln] = f2bf(v1 - bf2f(h1));
  }
  __syncthreads();

  // ---- jx = dta * (u0@wout^T): h_dot = jx, curr -> v bufs ----
  acc0 = (f4_t){0.f, 0.f, 0.f, 0.f};
  acc1 = (f4_t){0.f, 0.f, 0.f, 0.f};
  GEMM2(acc0, acc1, u_hi, u_lo, wof, 8);
#pragma unroll
  for (int r = 0; r < 4; ++r) {
    int row = lq * 4 + r;
    float v0 = dta0[r] * acc0[r];
    float v1 = dta1[r] * acc1[r];
    hd0[r] = v0; hd1[r] = v1;
    short h0 = f2bf(v0), h1 = f2bf(v1);
    v_hi[row][cbase + ln]      = h0;  v_lo[row][cbase + ln]      = f2bf(v0 - bf2f(h0));
    v_hi[row][cbase + 16 + ln] = h1;  v_lo[row][cbase + 16 + ln] = f2bf(v1 - bf2f(h1));
  }
  __syncthreads();

  // ---- 8x: curr <- dta*((dre*(curr@wh^T))@wout^T); h_dot += curr ----
  for (int it = 0; it < 8; ++it) {
    acc0 = (f4_t){0.f, 0.f, 0.f, 0.f};
    acc1 = (f4_t){0.f, 0.f, 0.f, 0.f};
    GEMM2(acc0, acc1, v_hi, v_lo, whf, 8);
#pragma unroll
    for (int r = 0; r < 4; ++r) {
      int row = lq * 4 + r;
      float v0 = dre0[r] * acc0[r];
      float v1 = dre1[r] * acc1[r];
      short h0 = f2bf(v0), h1 = f2bf(v1);
      u_hi[row][cbase + ln]      = h0;  u_lo[row][cbase + ln]      = f2bf(v0 - bf2f(h0));
      u_hi[row][cbase + 16 + ln] = h1;  u_lo[row][cbase + 16 + ln] = f2bf(v1 - bf2f(h1));
    }
    __syncthreads();

    acc0 = (f4_t){0.f, 0.f, 0.f, 0.f};
    acc1 = (f4_t){0.f, 0.f, 0.f, 0.f};
    GEMM2(acc0, acc1, u_hi, u_lo, wof, 8);
#pragma unroll
    for (int r = 0; r < 4; ++r) {
      int row = lq * 4 + r;
      float v0 = dta0[r] * acc0[r];
      float v1 = dta1[r] * acc1[r];
      hd0[r] += v0; hd1[r] += v1;
      if (it < 7) {
        short h0 = f2bf(v0), h1 = f2bf(v1);
        v_hi[row][cbase + ln]      = h0;  v_lo[row][cbase + ln]      = f2bf(v0 - bf2f(h0));
        v_hi[row][cbase + 16 + ln] = h1;  v_lo[row][cbase + 16 + ln] = f2bf(v1 - bf2f(h1));
      }
    }
    __syncthreads();
  }

  // ---- epilogue: fp32 out ----
#pragma unroll
  for (int r = 0; r < 4; ++r) {
    int row = lq * 4 + r;
    out[(size_t)(r0 + row) * H_ + cbase + ln]      = hd0[r];
    out[(size_t)(r0 + row) * H_ + cbase + 16 + ln] = hd1[r];
  }
}

extern "C" void kernel_launch(void* const* d_in, const int* in_sizes, int n_in,
                              void* d_out, int out_size, void* d_ws, size_t ws_size,
                              hipStream_t stream) {
  const float* h_g  = (const float*)d_in[0];
  const float* x_g  = (const float*)d_in[1];
  const float* xd_g = (const float*)d_in[2];
  const float* wx   = (const float*)d_in[3];
  const float* wh   = (const float*)d_in[4];
  const float* wo   = (const float*)d_in[5];
  const float* b0   = (const float*)d_in[6];
  const float* b1   = (const float*)d_in[7];
  prep_frag<<<dim3(72), dim3(256), 0, stream>>>(wh, wo, wx);
  jacde_mfma<<<dim3(B_ / 16), dim3(512), 0, stream>>>(
      h_g, x_g, xd_g, wx, wh, b0, b1, (float*)d_out);
}

// Round 6
// 89.507 us; speedup vs baseline: 2.6238x; 1.0708x over previous
//
#include <hip/hip_runtime.h>
#include <math.h>

#define B_  2048
#define H_  256
#define IN_ 64

typedef __attribute__((ext_vector_type(8))) short bf8_t;   // 8 x bf16 (4 VGPR)
typedef __attribute__((ext_vector_type(4))) short s4_t;
typedef __attribute__((ext_vector_type(4))) float f4_t;

#define MFMA_BF16(a, b, c) __builtin_amdgcn_mfma_f32_16x16x32_bf16((a), (b), (c), 0, 0, 0)

__device__ __forceinline__ short f2bf(float f) {         // rne
  union { float f; unsigned u; } v; v.f = f;
  unsigned u = v.u + 0x7fffu + ((v.u >> 16) & 1u);
  return (short)(u >> 16);
}
__device__ __forceinline__ float bf2f(short s) {
  union { unsigned u; float f; } v; v.u = ((unsigned)(unsigned short)s) << 16;
  return v.f;
}

// Pre-split weights in MFMA B-fragment layout: element j of fragment
// [(g*NKS+ks)*64+lane] is W[c][k], c = g*16 + (lane&15), k = ks*32 + (lane>>4)*8 + j.
__device__ __align__(16) short g_whf[2][65536];   // [hi/lo] 256x256
__device__ __align__(16) short g_wof[2][65536];   // [hi/lo] 256x256
__device__ __align__(16) short g_wxf[2][16384];   // [hi/lo] 256x64

__global__ void prep_frag(const float* __restrict__ wh, const float* __restrict__ wo,
                          const float* __restrict__ wx) {
  int tid = blockIdx.x * 256 + threadIdx.x;       // 72*256 = 18432
  const float* W; short* Dh; short* Dl; int ld, ksh, o8;
  if (tid < 8192)       { W = wh; Dh = g_whf[0]; Dl = g_whf[1]; ld = 256; ksh = 3; o8 = tid; }
  else if (tid < 16384) { W = wo; Dh = g_wof[0]; Dl = g_wof[1]; ld = 256; ksh = 3; o8 = tid - 8192; }
  else if (tid < 18432) { W = wx; Dh = g_wxf[0]; Dl = g_wxf[1]; ld = 64;  ksh = 1; o8 = tid - 16384; }
  else return;
  int lane = o8 & 63;
  int gks = o8 >> 6;
  int g = gks >> ksh, ks = gks & ((1 << ksh) - 1);
  int c = g * 16 + (lane & 15);
  int k0 = ks * 32 + ((lane >> 4) & 3) * 8;
  const float* p = W + (size_t)c * ld + k0;
  bf8_t hi, lo;
#pragma unroll
  for (int j = 0; j < 8; ++j) {
    float f = p[j];
    short h = f2bf(f);
    hi[j] = h; lo[j] = f2bf(f - bf2f(h));
  }
  *reinterpret_cast<bf8_t*>(Dh + (size_t)o8 * 8) = hi;
  *reinterpret_cast<bf8_t*>(Dl + (size_t)o8 * 8) = lo;
}

// 3-term split GEMM (A-hi/lo x W-hi/lo), odd/even-ks partial accs for ILP
#define GEMM3(A0, A1, AH, AL, WH, WL, NK) do {                                  \
  f4_t q0 = {0.f,0.f,0.f,0.f}, q1 = {0.f,0.f,0.f,0.f};                          \
  _Pragma("unroll")                                                             \
  for (int ks = 0; ks < (NK); ++ks) {                                           \
    bf8_t ah = *reinterpret_cast<const bf8_t*>(&AH[ln][ks * 32 + lq * 8]);      \
    bf8_t al = *reinterpret_cast<const bf8_t*>(&AL[ln][ks * 32 + lq * 8]);      \
    if (ks & 1) {                                                               \
      q0 = MFMA_BF16(ah, WH[0][ks], q0); q0 = MFMA_BF16(ah, WL[0][ks], q0);     \
      q0 = MFMA_BF16(al, WH[0][ks], q0);                                        \
      q1 = MFMA_BF16(ah, WH[1][ks], q1); q1 = MFMA_BF16(ah, WL[1][ks], q1);     \
      q1 = MFMA_BF16(al, WH[1][ks], q1);                                        \
    } else {                                                                    \
      A0 = MFMA_BF16(ah, WH[0][ks], A0); A0 = MFMA_BF16(ah, WL[0][ks], A0);     \
      A0 = MFMA_BF16(al, WH[0][ks], A0);                                        \
      A1 = MFMA_BF16(ah, WH[1][ks], A1); A1 = MFMA_BF16(ah, WL[1][ks], A1);     \
      A1 = MFMA_BF16(al, WH[1][ks], A1);                                        \
    }                                                                           \
  }                                                                             \
  A0 = A0 + q0; A1 = A1 + q1; } while (0)

// 2-term split GEMM (A-hi/lo x W-hi), odd/even-ks partial accs
#define GEMM2(A0, A1, AH, AL, WH, NK) do {                                      \
  f4_t q0 = {0.f,0.f,0.f,0.f}, q1 = {0.f,0.f,0.f,0.f};                          \
  _Pragma("unroll")                                                             \
  for (int ks = 0; ks < (NK); ++ks) {                                           \
    bf8_t ah = *reinterpret_cast<const bf8_t*>(&AH[ln][ks * 32 + lq * 8]);      \
    bf8_t al = *reinterpret_cast<const bf8_t*>(&AL[ln][ks * 32 + lq * 8]);      \
    if (ks & 1) {                                                               \
      q0 = MFMA_BF16(ah, WH[0][ks], q0); q0 = MFMA_BF16(al, WH[0][ks], q0);     \
      q1 = MFMA_BF16(ah, WH[1][ks], q1); q1 = MFMA_BF16(al, WH[1][ks], q1);     \
    } else {                                                                    \
      A0 = MFMA_BF16(ah, WH[0][ks], A0); A0 = MFMA_BF16(al, WH[0][ks], A0);     \
      A1 = MFMA_BF16(ah, WH[1][ks], A1); A1 = MFMA_BF16(al, WH[1][ks], A1);     \
    }                                                                           \
  }                                                                             \
  A0 = A0 + q0; A1 = A1 + q1; } while (0)

// 1-term GEMM (A-hi x W-hi) for the contraction chain: terms shrink geometrically,
// W-hi truncation (already present in R5, absmax 2 ULP) dominates; A truncation
// adds a comparable 2^-9 rel term -> predicted absmax ~0.03 < 0.054 budget.
#define GEMM1(A0, A1, AH, WH, NK) do {                                          \
  f4_t q0 = {0.f,0.f,0.f,0.f}, q1 = {0.f,0.f,0.f,0.f};                          \
  _Pragma("unroll")                                                             \
  for (int ks = 0; ks < (NK); ++ks) {                                           \
    bf8_t ah = *reinterpret_cast<const bf8_t*>(&AH[ln][ks * 32 + lq * 8]);      \
    if (ks & 1) {                                                               \
      q0 = MFMA_BF16(ah, WH[0][ks], q0);                                        \
      q1 = MFMA_BF16(ah, WH[1][ks], q1);                                        \
    } else {                                                                    \
      A0 = MFMA_BF16(ah, WH[0][ks], A0);                                        \
      A1 = MFMA_BF16(ah, WH[1][ks], A1);                                        \
    }                                                                           \
  }                                                                             \
  A0 = A0 + q0; A1 = A1 + q1; } while (0)

__global__ __launch_bounds__(512, 2) void jacde_mfma(
    const float* __restrict__ h_g, const float* __restrict__ x_g,
    const float* __restrict__ xd_g, const float* __restrict__ wx,
    const float* __restrict__ wh, const float* __restrict__ b0,
    const float* __restrict__ b1, float* __restrict__ out) {

  __shared__ short h_hi[16][264], h_lo[16][264];
  __shared__ short x_hi[16][72],  x_lo[16][72];
  __shared__ short xd_hi[16][72], xd_lo[16][72];
  __shared__ short u_hi[16][264], u_lo[16][264];
  __shared__ short v_hi[16][264];
  __shared__ float l1_t[16][264];
  __shared__ int   fix_cnt;
  __shared__ int   fix_list[64];

  const int tid  = threadIdx.x;
  const int wv   = tid >> 6;
  const int lane = tid & 63;
  const int ln   = lane & 15;       // A row / C col-within-tile
  const int lq   = lane >> 4;       // quad
  const int r0   = blockIdx.x * 16; // batch-row base
  const int cbase = wv * 32;        // wave's output-column base

  if (tid == 0) fix_cnt = 0;

  // ---- stage activations to split-bf16 LDS ----
  for (int c = tid; c < 16 * 64; c += 512) {
    int r = c >> 6, k4 = (c & 63) * 4;
    f4_t v = *reinterpret_cast<const f4_t*>(h_g + (size_t)(r0 + r) * H_ + k4);
    s4_t shv, slv;
#pragma unroll
    for (int j = 0; j < 4; ++j) { short h = f2bf(v[j]); shv[j] = h; slv[j] = f2bf(v[j] - bf2f(h)); }
    *reinterpret_cast<s4_t*>(&h_hi[r][k4]) = shv;
    *reinterpret_cast<s4_t*>(&h_lo[r][k4]) = slv;
  }
  {
    int t2 = tid & 255;
    const float* src = (tid < 256) ? x_g : xd_g;
    short (*dh)[72] = (tid < 256) ? x_hi : xd_hi;
    short (*dl)[72] = (tid < 256) ? x_lo : xd_lo;
    int r = t2 >> 4, k4 = (t2 & 15) * 4;
    f4_t v = *reinterpret_cast<const f4_t*>(src + (size_t)(r0 + r) * IN_ + k4);
    s4_t shv, slv;
#pragma unroll
    for (int j = 0; j < 4; ++j) { short h = f2bf(v[j]); shv[j] = h; slv[j] = f2bf(v[j] - bf2f(h)); }
    *reinterpret_cast<s4_t*>(&dh[r][k4]) = shv;
    *reinterpret_cast<s4_t*>(&dl[r][k4]) = slv;
  }

  // ---- persistent weight-hi fragments (live through all 19 GEMM steps) ----
  bf8_t whf[2][8], wof[2][8];
  f4_t acc0, acc1, sacc0, sacc1;
  float dre0[4], dre1[4], dta0[4], dta1[4], hd0[4], hd1[4];

  // ---- stage 1: l1 = x@wx^T + h@wh^T + b0 (3-term);  s = xdot@wx^T (3-term) ----
  {
    bf8_t whl[2][8], wxh[2][2], wxl[2][2];
#pragma unroll
    for (int t = 0; t < 2; ++t) {
      int gb = wv * 2 + t;
#pragma unroll
      for (int ks = 0; ks < 8; ++ks) {
        int off = ((gb * 8 + ks) * 64 + lane) * 8;
        whf[t][ks] = *reinterpret_cast<const bf8_t*>(&g_whf[0][off]);
        whl[t][ks] = *reinterpret_cast<const bf8_t*>(&g_whf[1][off]);
      }
#pragma unroll
      for (int ks = 0; ks < 2; ++ks) {
        int off = ((gb * 2 + ks) * 64 + lane) * 8;
        wxh[t][ks] = *reinterpret_cast<const bf8_t*>(&g_wxf[0][off]);
        wxl[t][ks] = *reinterpret_cast<const bf8_t*>(&g_wxf[1][off]);
      }
    }
    __syncthreads();   // activations staged

    float bv0 = b0[cbase + ln], bv1 = b0[cbase + 16 + ln];
    acc0 = (f4_t){bv0, bv0, bv0, bv0};
    acc1 = (f4_t){bv1, bv1, bv1, bv1};
    GEMM3(acc0, acc1, h_hi, h_lo, whf, whl, 8);
    GEMM3(acc0, acc1, x_hi, x_lo, wxh, wxl, 2);
    sacc0 = (f4_t){0.f, 0.f, 0.f, 0.f};
    sacc1 = (f4_t){0.f, 0.f, 0.f, 0.f};
    GEMM3(sacc0, sacc1, xd_hi, xd_lo, wxh, wxl, 2);
#pragma unroll
    for (int r = 0; r < 4; ++r) {   // C/D: col=lane&15, row=quad*4+reg [m89]
      l1_t[lq * 4 + r][cbase + ln]      = acc0[r];
      l1_t[lq * 4 + r][cbase + 16 + ln] = acc1[r];
    }
  }
  __syncthreads();

  // ---- fp64 fixup of near-zero l1 (hard relu gate must match fp64 anchor) ----
  for (int e = tid; e < 16 * 256; e += 512) {
    int r = e >> 8, c = e & 255;
    if (fabsf(l1_t[r][c]) < 1e-4f) {
      int idx = atomicAdd(&fix_cnt, 1);
      if (idx < 64) fix_list[idx] = (r << 8) | c;
    }
  }
  __syncthreads();
  {
    int nfix = min(fix_cnt, 64);
    for (int e = wv; e < nfix; e += 8) {
      int rc = fix_list[e];
      int r = rc >> 8, c = rc & 255;
      const float* hrow = h_g + (size_t)(r0 + r) * H_;
      const float* wrow = wh + (size_t)c * H_;
      double sum = (double)hrow[lane]       * (double)wrow[lane]
                 + (double)hrow[lane + 64]  * (double)wrow[lane + 64]
                 + (double)hrow[lane + 128] * (double)wrow[lane + 128]
                 + (double)hrow[lane + 192] * (double)wrow[lane + 192]
                 + (double)x_g[(size_t)(r0 + r) * IN_ + lane] * (double)wx[(size_t)c * IN_ + lane];
#pragma unroll
      for (int m = 32; m; m >>= 1) sum += __shfl_xor(sum, m);
      if (lane == 0) l1_t[r][c] = (float)(sum + (double)b0[c]);
    }
  }
  __syncthreads();

  // ---- gates: relu_val (split) to u bufs; dre into registers at wave positions ----
  for (int e = tid; e < 16 * 256; e += 512) {
    int r = e >> 8, c = e & 255;
    float l1 = l1_t[r][c];
    float rv = l1 > 0.f ? l1 : 0.f;
    short hi = f2bf(rv);
    u_hi[r][c] = hi;
    u_lo[r][c] = f2bf(rv - bf2f(hi));
  }
#pragma unroll
  for (int r = 0; r < 4; ++r) {
    dre0[r] = (l1_t[lq * 4 + r][cbase + ln]      > 0.f) ? 1.f : 0.f;
    dre1[r] = (l1_t[lq * 4 + r][cbase + 16 + ln] > 0.f) ? 1.f : 0.f;
  }
  __syncthreads();

  // ---- stage 2: lout = relu@wout^T + b1 (3-term) -> dtanh ----
  {
    bf8_t wol[2][8];
#pragma unroll
    for (int t = 0; t < 2; ++t) {
      int gb = wv * 2 + t;
#pragma unroll
      for (int ks = 0; ks < 8; ++ks) {
        int off = ((gb * 8 + ks) * 64 + lane) * 8;
        wof[t][ks] = *reinterpret_cast<const bf8_t*>(&g_wof[0][off]);
        wol[t][ks] = *reinterpret_cast<const bf8_t*>(&g_wof[1][off]);
      }
    }
    float bv0 = b1[cbase + ln], bv1 = b1[cbase + 16 + ln];
    acc0 = (f4_t){bv0, bv0, bv0, bv0};
    acc1 = (f4_t){bv1, bv1, bv1, bv1};
    GEMM3(acc0, acc1, u_hi, u_lo, wof, wol, 8);
#pragma unroll
    for (int r = 0; r < 4; ++r) {
      float t0 = tanhf(acc0[r]);
      float t1 = tanhf(acc1[r]);
      dta0[r] = 1.f - t0 * t0;
      dta1[r] = 1.f - t1 * t1;
    }
  }
  __syncthreads();   // all waves done reading relu from u bufs

  // ---- u0 = dre * s (split write at wave positions) ----
#pragma unroll
  for (int r = 0; r < 4; ++r) {
    int row = lq * 4 + r;
    float v0 = dre0[r] * sacc0[r];
    float v1 = dre1[r] * sacc1[r];
    short h0 = f2bf(v0), h1 = f2bf(v1);
    u_hi[row][cbase + ln]      = h0;  u_lo[row][cbase + ln]      = f2bf(v0 - bf2f(h0));
    u_hi[row][cbase + 16 + ln] = h1;  u_lo[row][cbase + 16 + ln] = f2bf(v1 - bf2f(h1));
  }
  __syncthreads();

  // ---- jx = dta * (u0@wout^T): h_dot = jx, curr -> v_hi (2-term: largest term) ----
  acc0 = (f4_t){0.f, 0.f, 0.f, 0.f};
  acc1 = (f4_t){0.f, 0.f, 0.f, 0.f};
  GEMM2(acc0, acc1, u_hi, u_lo, wof, 8);
#pragma unroll
  for (int r = 0; r < 4; ++r) {
    int row = lq * 4 + r;
    float v0 = dta0[r] * acc0[r];
    float v1 = dta1[r] * acc1[r];
    hd0[r] = v0; hd1[r] = v1;
    v_hi[row][cbase + ln]      = f2bf(v0);
    v_hi[row][cbase + 16 + ln] = f2bf(v1);
  }
  __syncthreads();

  // ---- 8x 1-term chain: curr <- dta*((dre*(curr@wh^T))@wout^T); h_dot += curr ----
  for (int it = 0; it < 8; ++it) {
    acc0 = (f4_t){0.f, 0.f, 0.f, 0.f};
    acc1 = (f4_t){0.f, 0.f, 0.f, 0.f};
    GEMM1(acc0, acc1, v_hi, whf, 8);
#pragma unroll
    for (int r = 0; r < 4; ++r) {
      int row = lq * 4 + r;
      u_hi[row][cbase + ln]      = f2bf(dre0[r] * acc0[r]);
      u_hi[row][cbase + 16 + ln] = f2bf(dre1[r] * acc1[r]);
    }
    __syncthreads();

    acc0 = (f4_t){0.f, 0.f, 0.f, 0.f};
    acc1 = (f4_t){0.f, 0.f, 0.f, 0.f};
    GEMM1(acc0, acc1, u_hi, wof, 8);
#pragma unroll
    for (int r = 0; r < 4; ++r) {
      int row = lq * 4 + r;
      float v0 = dta0[r] * acc0[r];
      float v1 = dta1[r] * acc1[r];
      hd0[r] += v0; hd1[r] += v1;
      if (it < 7) {
        v_hi[row][cbase + ln]      = f2bf(v0);
        v_hi[row][cbase + 16 + ln] = f2bf(v1);
      }
    }
    __syncthreads();
  }

  // ---- epilogue: fp32 out ----
#pragma unroll
  for (int r = 0; r < 4; ++r) {
    int row = lq * 4 + r;
    out[(size_t)(r0 + row) * H_ + cbase + ln]      = hd0[r];
    out[(size_t)(r0 + row) * H_ + cbase + 16 + ln] = hd1[r];
  }
}

extern "C" void kernel_launch(void* const* d_in, const int* in_sizes, int n_in,
                              void* d_out, int out_size, void* d_ws, size_t ws_size,
                              hipStream_t stream) {
  const float* h_g  = (const float*)d_in[0];
  const float* x_g  = (const float*)d_in[1];
  const float* xd_g = (const float*)d_in[2];
  const float* wx   = (const float*)d_in[3];
  const float* wh   = (const float*)d_in[4];
  const float* wo   = (const float*)d_in[5];
  const float* b0   = (const float*)d_in[6];
  const float* b1   = (const float*)d_in[7];
  prep_frag<<<dim3(72), dim3(256), 0, stream>>>(wh, wo, wx);
  jacde_mfma<<<dim3(B_ / 16), dim3(512), 0, stream>>>(
      h_g, x_g, xd_g, wx, wh, b0, b1, (float*)d_out);
}